// Round 6
// baseline (505.062 us; speedup 1.0000x reference)
//
#include <hip/hip_runtime.h>
#include <math.h>

#define NK 512                      // N_EMB
#define NPTS (32*64*64)             // 131072 points
#define NELEM (32*64*64*64)         // 8388608 elements of z

// flat d_out offsets (return order: loss, z_q, perplexity, encodings, codebook)
#define OFF_LOSS 0
#define OFF_ZQ   1
#define OFF_PERP (1 + NELEM)
#define OFF_ENC  (2 + NELEM)
#define OFF_CB   (2 + NELEM + (size_t)NPTS * NK)

// ws layout: [0,2048) hist int[512] | [2048,2056) lossAcc double |
//            [4096, +128KB) wTT f32[64 chunks][64 d][8 codes] | then bnd f32[512]

// ---- prep: wTT[(c*64+d)*8+j] = w[c*8+j][d]; bnd[k] = sum_d w[k][d]^2 (sequential d) ----
__global__ __launch_bounds__(256) void vq_prep(const float* __restrict__ wg,
                                               float* __restrict__ wTT,
                                               float* __restrict__ bnd) {
    __shared__ float tl[64 * 65];
    const int t = threadIdx.x;
    const int kbase = blockIdx.x * 64;          // 8 blocks x 64 codes
    #pragma unroll
    for (int it = 0; it < 16; ++it) {
        int i = it * 256 + t;
        int k = i >> 6, d = i & 63;
        tl[k * 65 + d] = wg[(size_t)(kbase + k) * 64 + d];
    }
    __syncthreads();
    #pragma unroll
    for (int it = 0; it < 16; ++it) {
        int i = it * 256 + t;
        int kk = i & 63, d = i >> 6;
        int k = kbase + kk;
        wTT[(size_t)((k >> 3) * 64 + d) * 8 + (k & 7)] = tl[kk * 65 + d];
    }
    if (t < 64) {
        float s = 0.f;
        #pragma unroll 4
        for (int d = 0; d < 64; ++d) {
            float v = tl[t * 65 + d];
            s = __fadd_rn(s, __fmul_rn(v, v));
        }
        bnd[kbase + t] = s;
    }
}

// Fused kernel: 1024 blocks x 256 threads. wave = one (b,h) row x half the codebook.
// lane = point. z in VGPRs (coalesced load, no transpose). Codes via scalar pipe
// (wave-uniform wTT reads -> s_load + v_fmac v,s,v). Inner loop: zero LDS/VMEM.
__global__ __launch_bounds__(256, 4) void vq_fused(const float* __restrict__ zg,
                                                   const float* __restrict__ wg,
                                                   const float* __restrict__ wTT,
                                                   const float* __restrict__ bndg,
                                                   float* __restrict__ out,
                                                   int* __restrict__ hist,
                                                   double* __restrict__ lossAcc) {
    const int t = threadIdx.x;
    const int wave = t >> 6;
    const int lane = t & 63;
    const int rowInBlk = wave >> 1;            // 0,1: which row of the block
    const int half = wave & 1;                 // code half: [half*256, half*256+256)
    const int r = blockIdx.x * 2 + rowInBlk;   // 2048 rows = (b,h)
    const int b = r >> 6;
    const int h = r & 63;
    const size_t base = (size_t)b * 262144 + (size_t)h * 64;   // + d*4096 + lane

    __shared__ float shv[4][64];
    __shared__ int   shi[4][64];
    __shared__ int   shm[2][64];

    // ---- z row into registers: lane p gets z[b, d, h, p] (coalesced per d) ----
    float zreg[64];
    #pragma unroll
    for (int d = 0; d < 64; ++d)
        zreg[d] = zg[base + (size_t)d * 4096 + lane];

    // ---- a = sum_d z^2 (sequential d, mul+add — matches reference) ----
    float a = 0.f;
    #pragma unroll
    for (int d = 0; d < 64; ++d)
        a = __fadd_rn(a, __fmul_rn(zreg[d], zreg[d]));

    const int shalf = __builtin_amdgcn_readfirstlane(half);
    const float* wbase = wTT + (size_t)shalf * 32 * 512;   // 32 chunks x 512 floats
    const float* bnb = bndg + shalf * 256;

    float best = INFINITY;
    int bidx = 0;

    #pragma unroll 1
    for (int cc = 0; cc < 32; ++cc) {
        const float* wrow = wbase + cc * 512;   // uniform -> scalar loads
        float acc[8];
        #pragma unroll
        for (int j = 0; j < 8; ++j) acc[j] = 0.f;

        #pragma unroll
        for (int d = 0; d < 64; ++d) {
            const float zv = zreg[d];
            #pragma unroll
            for (int j = 0; j < 8; ++j)
                acc[j] = fmaf(zv, wrow[d * 8 + j], acc[j]);
        }

        // dist = fl(fl(a+b) - 2*dot); ascending k + strict < = first-index
        #pragma unroll
        for (int j = 0; j < 8; ++j) {
            float dist = __fsub_rn(__fadd_rn(a, bnb[cc * 8 + j]), 2.0f * acc[j]);
            int k = shalf * 256 + cc * 8 + j;
            if (dist < best) { best = dist; bidx = k; }
        }
    }

    // ---- cross-wave merge (wave0 range k<256 < wave1 range; strict < keeps first-index) ----
    shv[wave][lane] = best;
    shi[wave][lane] = bidx;
    __syncthreads();
    const int w0 = rowInBlk * 2;
    float v0 = shv[w0][lane];     int i0 = shi[w0][lane];
    float v1 = shv[w0 + 1][lane]; int i1 = shi[w0 + 1][lane];
    const int mi = (v1 < v0) ? i1 : i0;

    if (half == 0) {
        shm[rowInBlk][lane] = mi;
        out[OFF_CB + (size_t)r * 64 + lane] = (float)mi;
        atomicAdd(&hist[mi], 1);
    }
    __syncthreads();

    // ---- encodings: each wave writes 32 one-hot rows, dense coalesced float4 ----
    {
        float* encb = out + OFF_ENC + ((size_t)r * 64) * 512;
        const int e0 = lane * 4;          // elements [e0,e0+4) and [256+e0,...)
        #pragma unroll 4
        for (int p = 0; p < 32; ++p) {
            int pt = shalf * 32 + p;
            int idx = shm[rowInBlk][pt];  // LDS broadcast
            float* erow = encb + (size_t)pt * 512;
            float4 A, B;
            A.x = (e0 + 0 == idx) ? 1.f : 0.f;
            A.y = (e0 + 1 == idx) ? 1.f : 0.f;
            A.z = (e0 + 2 == idx) ? 1.f : 0.f;
            A.w = (e0 + 3 == idx) ? 1.f : 0.f;
            B.x = (e0 + 256 == idx) ? 1.f : 0.f;
            B.y = (e0 + 257 == idx) ? 1.f : 0.f;
            B.z = (e0 + 258 == idx) ? 1.f : 0.f;
            B.w = (e0 + 259 == idx) ? 1.f : 0.f;
            *(float4*)(erow + e0) = A;
            *(float4*)(erow + 256 + e0) = B;
        }
    }

    // ---- z_q (straight-through) + loss partial: each wave does its 32-d half ----
    float lsum = 0.f;
    {
        const int dlo = shalf * 32;
        const float4* wr4 = (const float4*)(wg + (size_t)mi * 64 + dlo);  // per-lane gather
        float q[32];
        #pragma unroll
        for (int e = 0; e < 8; ++e) {
            float4 v = wr4[e];
            q[4 * e + 0] = v.x; q[4 * e + 1] = v.y;
            q[4 * e + 2] = v.z; q[4 * e + 3] = v.w;
        }
        float* zq = out + OFF_ZQ + base;
        #pragma unroll
        for (int dd = 0; dd < 32; ++dd) {
            int d = dlo + dd;
            float zv = zreg[d];
            float diff = __fsub_rn(q[dd], zv);
            lsum = __fadd_rn(lsum, __fmul_rn(diff, diff));
            zq[(size_t)d * 4096 + lane] = __fadd_rn(zv, diff);
        }
    }
    #pragma unroll
    for (int off = 32; off > 0; off >>= 1)
        lsum += __shfl_down(lsum, off);
    if (lane == 0)
        atomicAdd(lossAcc, (double)lsum);
}

__global__ __launch_bounds__(512) void vq_finalize(const int* __restrict__ hist,
                                                   const double* __restrict__ lossAcc,
                                                   float* __restrict__ out) {
    __shared__ float sh[512];
    const int t = threadIdx.x;
    float p = (float)hist[t] / (float)NPTS;   // exact: /2^17
    sh[t] = __fmul_rn(p, logf(__fadd_rn(p, 1e-10f)));
    __syncthreads();
    for (int s = 256; s > 0; s >>= 1) {
        if (t < s) sh[t] += sh[t + s];
        __syncthreads();
    }
    if (t == 0) {
        float m = (float)(*lossAcc / (double)NELEM);
        out[OFF_LOSS] = __fadd_rn(m, __fmul_rn(0.25f, m));
        out[OFF_PERP] = expf(-sh[0]);
    }
}

extern "C" void kernel_launch(void* const* d_in, const int* in_sizes, int n_in,
                              void* d_out, int out_size, void* d_ws, size_t ws_size,
                              hipStream_t stream) {
    const float* z = (const float*)d_in[0];
    const float* w = (const float*)d_in[1];
    float* out = (float*)d_out;
    int* hist = (int*)d_ws;
    double* lossAcc = (double*)((char*)d_ws + 2048);
    float* wTT = (float*)((char*)d_ws + 4096);
    float* bnd = wTT + 64 * 512;

    (void)hipMemsetAsync(d_ws, 0, 4096, stream);
    vq_prep<<<8, 256, 0, stream>>>(w, wTT, bnd);
    vq_fused<<<1024, 256, 0, stream>>>(z, w, wTT, bnd, out, hist, lossAcc);
    vq_finalize<<<1, 512, 0, stream>>>(hist, lossAcc, out);
}